// Round 7
// baseline (288.931 us; speedup 1.0000x reference)
//
#include <hip/hip_runtime.h>
#include <hip/hip_bf16.h>
#include <hip/hip_cooperative_groups.h>

namespace cg = cooperative_groups;

#define NPTS 8192
#define NSL 64          // j-slices (128 points each)
#define HF 96.0f
#define NBLK 512        // 2 blocks/CU -> co-residency guaranteed for coop launch
#define MED_UNITS 1152  // 96 rows x 12 col-groups of 8

// Workspace layout (bytes):
//   0        : float  nn2p[64][8192]   partial min d2 (unclamped) per (slice, i)
//   2097152  : int    rkp [64][8192]   partial pz-rank per (slice, i)
//   4194304  : float2 pxy[8192]        (px,py) sorted by pz
//   4259840  : float  pzs[8192]
//   4292608  : double sum_part[32]     per-block partial sums of nn_dist
// No init / atomics: every cell written exactly once before being read.

// monotone (z, idx) -> u64 key; strict total order, one u64 compare per pair
__device__ __forceinline__ unsigned long long zkey(float z, int idx) {
    unsigned u = __float_as_uint(z);
    unsigned m = (unsigned)((int)u >> 31) | 0x80000000u;  // neg: FFFFFFFF, pos: 80000000
    return ((unsigned long long)(u ^ m) << 13) | (unsigned)idx;
}

// Single cooperative kernel: phase1 NN/rank partials -> grid.sync ->
// phase2 reduce+scatter+sum -> grid.sync -> phase3 delta2 + per-cell median.
// Rationale: rounds 4-6 showed totals are dominated by per-launch overhead
// (~5us/launch observed R4->R5), not kernel interiors; this removes 2 launches.
__global__ __launch_bounds__(256) void k_all(const float* __restrict__ pts,
                                             float* __restrict__ nn2p,
                                             int* __restrict__ rkp,
                                             float2* __restrict__ pxy,
                                             float* __restrict__ pzs,
                                             double* __restrict__ sum_part,
                                             float* __restrict__ out) {
    cg::grid_group grid = cg::this_grid();
    __shared__ float4 sj[128];               // (-2x, -2y, -2z, sq)
    __shared__ unsigned long long kj[128];   // z-order key
    __shared__ unsigned long long bal[8][4][32];  // [cell][wave][chunk]
    __shared__ double sw[4];
    __shared__ float s_dd;

    const int tid = threadIdx.x;
    const int b = blockIdx.x;

    // ---------------- Phase 1: NN-min + rank partials (R6 structure) ---------
    {
        const int bx = b >> 6;        // 0..7  (i-block of 1024)
        const int by = b & 63;        // 0..63 (j-slice of 128)
        const int j0 = by * 128;
        if (tid < 128) {
            int j = j0 + tid;
            float x = pts[3 * j + 0] * HF;
            float y = pts[3 * j + 1] * HF;
            float z = pts[3 * j + 2] * HF;
            sj[tid] = make_float4(-2.0f * x, -2.0f * y, -2.0f * z,
                                  x * x + y * y + z * z);
            kj[tid] = zkey(z, j);
        }
        float xi[4], yi[4], zi[4], sqi[4];
        unsigned long long ki[4];
        int iq[4];
        #pragma unroll
        for (int q = 0; q < 4; ++q) {
            int i = bx * 1024 + q * 256 + tid;
            iq[q] = i;
            float x = pts[3 * i + 0] * HF;
            float y = pts[3 * i + 1] * HF;
            float z = pts[3 * i + 2] * HF;
            xi[q] = x; yi[q] = y; zi[q] = z;
            sqi[q] = x * x + y * y + z * z;
            ki[q] = zkey(z, i);
        }
        __syncthreads();

        float mn[4] = {3.0e38f, 3.0e38f, 3.0e38f, 3.0e38f};
        int rk[4] = {0, 0, 0, 0};
        if ((by >> 3) != bx) {        // no self-pair possible: block-uniform
            #pragma unroll 8
            for (int k = 0; k < 128; ++k) {
                const float4 p = sj[k];
                const unsigned long long pk = kj[k];
                #pragma unroll
                for (int q = 0; q < 4; ++q) {
                    // reference formula: sq_i + sq_j - 2*dot
                    float d2 = fmaf(p.x, xi[q], fmaf(p.y, yi[q],
                                fmaf(p.z, zi[q], sqi[q] + p.w)));
                    mn[q] = fminf(mn[q], d2);
                    rk[q] += (int)(pk < ki[q]);   // stable pz rank
                }
            }
        } else {
            int sk_[4];
            #pragma unroll
            for (int q = 0; q < 4; ++q) sk_[q] = iq[q] - j0;  // self k (may be OOR)
            #pragma unroll 8
            for (int k = 0; k < 128; ++k) {
                const float4 p = sj[k];
                const unsigned long long pk = kj[k];
                #pragma unroll
                for (int q = 0; q < 4; ++q) {
                    float d2 = fmaf(p.x, xi[q], fmaf(p.y, yi[q],
                                fmaf(p.z, zi[q], sqi[q] + p.w)));
                    if (k != sk_[q]) mn[q] = fminf(mn[q], d2);
                    rk[q] += (int)(pk < ki[q]);
                }
            }
        }
        #pragma unroll
        for (int q = 0; q < 4; ++q) {
            nn2p[by * NPTS + iq[q]] = mn[q];   // written exactly once
            rkp [by * NPTS + iq[q]] = rk[q];
        }
    }
    __threadfence();   // device-scope release (cross-XCD visibility, G16)
    grid.sync();

    // ---------------- Phase 2: reduce partials, scatter, partial sums --------
    if (b < 32) {
        const int i = b * 256 + tid;
        float mn = 3.0e38f;
        int rk = 0;
        #pragma unroll 8
        for (int s = 0; s < NSL; ++s) {
            mn = fminf(mn, nn2p[s * NPTS + i]);   // coalesced
            rk += rkp[s * NPTS + i];
        }
        // clamp commutes with min across slices: min_s max(m_s,0)==max(min_s,0)
        const float nnd = sqrtf(fmaxf(mn, 0.0f));
        pxy[rk] = make_float2(pts[3 * i + 0] * HF, pts[3 * i + 1] * HF);
        pzs[rk] = pts[3 * i + 2] * HF;

        double acc = (double)nnd;
        #pragma unroll
        for (int off = 32; off > 0; off >>= 1) acc += __shfl_down(acc, off, 64);
        if ((tid & 63) == 0) sw[tid >> 6] = acc;
        __syncthreads();
        if (tid == 0) sum_part[b] = sw[0] + sw[1] + sw[2] + sw[3];
    }
    __threadfence();
    grid.sync();

    // ---------------- Phase 3: delta2 + per-cell medians ---------------------
    // delta2 from the 32 double partials: deterministic (same values, same
    // order) -> identical in every block.
    if (tid == 0) {
        double s = 0.0;
        #pragma unroll
        for (int k = 0; k < 32; ++k) s += sum_part[k];
        float mean = (float)(s / (double)NPTS);
        float avg = 3.0f * mean;     // M_FACTOR * mean
        s_dd = 3.0f * avg;           // M_FACTOR * avg
    }
    __syncthreads();
    const float d = s_dd;
    const int lane = tid & 63;
    const int w = tid >> 6;

    // NOTE: replicates reference exactly: px upper bound uses Yr (row-uniform).
    for (int u = b; u < MED_UNITS; u += NBLK) {
        const int row = u / 12;
        const int cgx = u % 12;
        const float Yf = (float)(row - 48);
        const float ylo = Yf - d, yhi = Yf + d, xhi = Yf + d;
        float xlo[8];
        #pragma unroll
        for (int c = 0; c < 8; ++c) xlo[c] = (float)(cgx * 8 + c - 48) - d;

        __syncthreads();   // protect bal reuse across units
        #pragma unroll 4
        for (int k = 0; k < 32; ++k) {
            float2 p = pxy[(k << 8) + tid];
            bool pre = (p.y >= ylo) && (p.y <= yhi) && (p.x <= xhi);
            unsigned long long bb[8];
            #pragma unroll
            for (int c = 0; c < 8; ++c) bb[c] = __ballot(pre && (p.x >= xlo[c]));
            if (lane == 0) {
                #pragma unroll
                for (int c = 0; c < 8; ++c) bal[c][w][k] = bb[c];
            }
        }
        __syncthreads();

        // wave w handles cells 2w and 2w+1; lanes 0..31 each own one chunk
        #pragma unroll
        for (int c2 = 0; c2 < 2; ++c2) {
            const int c = w * 2 + c2;
            const int l = (lane < 32) ? lane : 31;
            const unsigned long long bw0 = bal[c][0][l];
            const unsigned long long bw1 = bal[c][1][l];
            const unsigned long long bw2 = bal[c][2][l];
            const unsigned long long bw3 = bal[c][3][l];
            const int cnt = __popcll(bw0) + __popcll(bw1) + __popcll(bw2) + __popcll(bw3);
            const int cl = (lane < 32) ? cnt : 0;
            int incl = cl;
            #pragma unroll
            for (int off = 1; off < 64; off <<= 1) {
                int v = __shfl_up(incl, off, 64);
                if (lane >= off) incl += v;
            }
            const int ct = __shfl(incl, 63, 64);  // total count c
            const int og = row * 96 + cgx * 8 + c;
            if (ct == 0) {
                if (lane == 0) out[og] = 0.0f;
                continue;
            }
            const int excl = incl - cl;
            float vv[2];
            #pragma unroll
            for (int sel = 0; sel < 2; ++sel) {
                const int target = sel ? (ct >> 1) : ((ct - 1) >> 1);
                const bool pred = (lane < 32) && (target >= excl) && (target < excl + cl);
                unsigned long long bm = __ballot(pred);
                int src = __ffsll(bm) - 1;  // exactly one lane holds the target
                float val = 0.0f;
                if (pred) {
                    int r = target - excl;
                    int pc0 = __popcll(bw0), pc1 = __popcll(bw1), pc2 = __popcll(bw2);
                    unsigned long long x;
                    int base;
                    if (r < pc0)              { x = bw0; base = 0; }
                    else if (r < pc0 + pc1)   { x = bw1; base = 64;  r -= pc0; }
                    else if (r < pc0+pc1+pc2) { x = bw2; base = 128; r -= pc0 + pc1; }
                    else                      { x = bw3; base = 192; r -= pc0 + pc1 + pc2; }
                    for (int q = 0; q < r; ++q) x &= x - 1;  // drop r lowest set bits
                    val = pzs[(l << 8) + base + (__ffsll(x) - 1)];
                }
                vv[sel] = __shfl(val, src, 64);
            }
            if (lane == 0) {
                float med = 0.5f * (vv[0] + vv[1]);
                out[og] = (med + 48.0f) * (1.0f / 96.0f);
            }
        }
    }
}

extern "C" void kernel_launch(void* const* d_in, const int* in_sizes, int n_in,
                              void* d_out, int out_size, void* d_ws, size_t ws_size,
                              hipStream_t stream) {
    const float* pts = (const float*)d_in[0];
    float* out = (float*)d_out;

    char* ws = (char*)d_ws;
    float* nn2p      = (float*)(ws + 0);
    int* rkp         = (int*)(ws + 2097152);
    float2* pxy      = (float2*)(ws + 4194304);
    float* pzs       = (float*)(ws + 4259840);
    double* sum_part = (double*)(ws + 4292608);

    void* args[] = {(void*)&pts, (void*)&nn2p, (void*)&rkp, (void*)&pxy,
                    (void*)&pzs, (void*)&sum_part, (void*)&out};
    hipLaunchCooperativeKernel((const void*)k_all, dim3(NBLK), dim3(256),
                               args, 0, stream);
}

// Round 8
// 114.399 us; speedup vs baseline: 2.5256x; 2.5256x over previous
//
#include <hip/hip_runtime.h>
#include <hip/hip_bf16.h>

#define NPTS 8192
#define NSL 64          // j-slices (128 points each)
#define HF 96.0f

// Workspace layout (bytes):
//   0        : float  nn2p[64][8192]   partial min d2 (unclamped) per (slice, i)
//   2097152  : int    rkp [64][8192]   partial pz-rank per (slice, i)
//   4194304  : float2 pxy[8192]        (px,py) sorted by pz
//   4259840  : float  pzs[8192]
//   4292608  : double sum_part[32]     per-block partial sums of nn_dist
// No init kernel / atomics: every cell written exactly once.
// R7 lesson: coop grid.sync costs ~100us/sync on 512 blocks -- 3 separate
// launches (~5us each) are far cheaper. Keep the 3-kernel structure.

// monotone (z, idx) -> u64 key; strict total order, one u64 compare per pair
__device__ __forceinline__ unsigned long long zkey(float z, int idx) {
    unsigned u = __float_as_uint(z);
    unsigned m = (unsigned)((int)u >> 31) | 0x80000000u;  // neg: FFFFFFFF, pos: 80000000
    return ((unsigned long long)(u ^ m) << 13) | (unsigned)idx;
}

// grid (32 i-blocks, 64 j-slices of 128), block 256 -> 2048 blocks, 8/CU.
// (R4 champion config: 107.5us total; R6's 4-i/pt variant measured equal.)
__global__ __launch_bounds__(256) void k_nn_rank(const float* __restrict__ pts,
                                                 float* __restrict__ nn2p,
                                                 int* __restrict__ rkp) {
    __shared__ float4 s4[128];               // (px, py, pz, sq)
    __shared__ unsigned long long sk[128];   // z-order key
    const int tid = threadIdx.x;
    const int bx = blockIdx.x, by = blockIdx.y;
    const int i = bx * 256 + tid;
    const int j0 = by * 128;
    if (tid < 128) {
        int j = j0 + tid;
        float x = pts[3 * j + 0] * HF;
        float y = pts[3 * j + 1] * HF;
        float z = pts[3 * j + 2] * HF;
        s4[tid] = make_float4(x, y, z, x * x + y * y + z * z);
        sk[tid] = zkey(z, j);
    }
    const float xi = pts[3 * i + 0] * HF;
    const float yi = pts[3 * i + 1] * HF;
    const float zi = pts[3 * i + 2] * HF;
    const float sqi = xi * xi + yi * yi + zi * zi;
    const unsigned long long ki = zkey(zi, i);
    __syncthreads();

    float mn = 3.0e38f;
    int rk = 0;
    // self-pair occurs iff this j-slice covers i; condition is wave-uniform
    // (tid>>7 constant within a wave), so no divergence.
    const bool has_self = (by == 2 * bx + (tid >> 7));
    if (!has_self) {
        #pragma unroll 8
        for (int k = 0; k < 128; ++k) {
            float4 p = s4[k];
            // reference formula: sq_i + sq_j - 2*dot
            float d2 = sqi + p.w - 2.0f * (xi * p.x + yi * p.y + zi * p.z);
            mn = fminf(mn, d2);
            rk += (int)(sk[k] < ki);   // stable pz rank (index tiebreak)
        }
    } else {
        const int self_k = tid & 127;
        #pragma unroll 8
        for (int k = 0; k < 128; ++k) {
            float4 p = s4[k];
            float d2 = sqi + p.w - 2.0f * (xi * p.x + yi * p.y + zi * p.z);
            if (k != self_k) mn = fminf(mn, d2);
            rk += (int)(sk[k] < ki);
        }
    }
    nn2p[by * NPTS + i] = mn;   // coalesced, written exactly once
    rkp [by * NPTS + i] = rk;
}

// grid 32, block 256. Reduce partials -> nn_dist + total rank; scatter into
// pz-sorted order; per-block double partial sum of nn_dist.
__global__ __launch_bounds__(256) void k_mid(const float* __restrict__ pts,
                                             const float* __restrict__ nn2p,
                                             const int* __restrict__ rkp,
                                             float2* __restrict__ pxy,
                                             float* __restrict__ pzs,
                                             double* __restrict__ sum_part) {
    const int t = threadIdx.x;
    const int i = blockIdx.x * 256 + t;
    float mn = 3.0e38f;
    int rk = 0;
    #pragma unroll 8
    for (int s = 0; s < NSL; ++s) {
        mn = fminf(mn, nn2p[s * NPTS + i]);   // coalesced across threads
        rk += rkp[s * NPTS + i];
    }
    // clamp commutes with min across slices: min_s max(m_s,0) == max(min_s,0)
    const float nnd = sqrtf(fmaxf(mn, 0.0f));
    pxy[rk] = make_float2(pts[3 * i + 0] * HF, pts[3 * i + 1] * HF);
    pzs[rk] = pts[3 * i + 2] * HF;

    double acc = (double)nnd;
    #pragma unroll
    for (int off = 32; off > 0; off >>= 1) acc += __shfl_down(acc, off, 64);
    __shared__ double sw[4];
    if ((t & 63) == 0) sw[t >> 6] = acc;
    __syncthreads();
    if (t == 0) sum_part[blockIdx.x] = sw[0] + sw[1] + sw[2] + sw[3];
}

// One block per (row, group of 16 cols): 6x96 = 576 blocks. vs the 8-col
// version this HALVES total pxy L2 traffic (74->37 MB) and halves per-CU
// load/precompute work (ballot count unchanged). Thread t owns point 256k+t
// of chunk k (pz-sorted) -> coalesced float2 loads. Membership as per-wave
// 64-bit ballots in LDS (16 KB); rank selection per-wave in the epilogue
// (wave w handles cells 4w..4w+3). delta2 finalized per-block from the 32
// double partials (deterministic -> identical in every block).
// NOTE: replicates reference exactly: px upper bound uses Yr (row-uniform), not Xr.
__global__ __launch_bounds__(256) void k_median(const float2* __restrict__ pxy,
                                                const float* __restrict__ pzs,
                                                const double* __restrict__ sum_part,
                                                float* __restrict__ out) {
    __shared__ unsigned long long bal[16][4][32];  // [cell][wave][chunk] = 16 KB
    __shared__ float s_dd;
    const int t = threadIdx.x;
    const int lane = t & 63;
    const int w = t >> 6;
    const int row = blockIdx.y;      // 96
    const int cgx = blockIdx.x;      // 6 col-groups of 16
    if (t == 0) {
        double s = 0.0;
        #pragma unroll
        for (int b = 0; b < 32; ++b) s += sum_part[b];
        float mean = (float)(s / (double)NPTS);
        float avg = 3.0f * mean;     // M_FACTOR * mean
        s_dd = 3.0f * avg;           // M_FACTOR * avg
    }
    __syncthreads();
    const float d = s_dd;
    const float Yf = (float)(row - 48);
    const float ylo = Yf - d, yhi = Yf + d, xhi = Yf + d;
    float xlo[16];
    #pragma unroll
    for (int c = 0; c < 16; ++c) xlo[c] = (float)(cgx * 16 + c - 48) - d;

    #pragma unroll 4
    for (int k = 0; k < 32; ++k) {
        float2 p = pxy[(k << 8) + t];
        bool pre = (p.y >= ylo) && (p.y <= yhi) && (p.x <= xhi);
        unsigned long long b[16];
        #pragma unroll
        for (int c = 0; c < 16; ++c) b[c] = __ballot(pre && (p.x >= xlo[c]));
        if (lane == 0) {
            #pragma unroll
            for (int c = 0; c < 16; ++c) bal[c][w][k] = b[c];
        }
    }
    __syncthreads();

    // wave w handles cells 4w..4w+3; lanes 0..31 each own one chunk
    #pragma unroll
    for (int c2 = 0; c2 < 4; ++c2) {
        const int c = w * 4 + c2;
        const int l = (lane < 32) ? lane : 31;
        const unsigned long long bw0 = bal[c][0][l];
        const unsigned long long bw1 = bal[c][1][l];
        const unsigned long long bw2 = bal[c][2][l];
        const unsigned long long bw3 = bal[c][3][l];
        const int cnt = __popcll(bw0) + __popcll(bw1) + __popcll(bw2) + __popcll(bw3);
        const int cl = (lane < 32) ? cnt : 0;
        int incl = cl;
        #pragma unroll
        for (int off = 1; off < 64; off <<= 1) {
            int v = __shfl_up(incl, off, 64);
            if (lane >= off) incl += v;
        }
        const int ct = __shfl(incl, 63, 64);  // total count c
        const int og = row * 96 + cgx * 16 + c;
        if (ct == 0) {
            if (lane == 0) out[og] = 0.0f;
            continue;
        }
        const int excl = incl - cl;
        float vv[2];
        #pragma unroll
        for (int sel = 0; sel < 2; ++sel) {
            const int target = sel ? (ct >> 1) : ((ct - 1) >> 1);
            const bool pred = (lane < 32) && (target >= excl) && (target < excl + cl);
            unsigned long long bm = __ballot(pred);
            int src = __ffsll(bm) - 1;  // exactly one lane holds the target
            float val = 0.0f;
            if (pred) {
                int r = target - excl;
                int pc0 = __popcll(bw0), pc1 = __popcll(bw1), pc2 = __popcll(bw2);
                unsigned long long x;
                int base;
                if (r < pc0)              { x = bw0; base = 0; }
                else if (r < pc0 + pc1)   { x = bw1; base = 64;  r -= pc0; }
                else if (r < pc0+pc1+pc2) { x = bw2; base = 128; r -= pc0 + pc1; }
                else                      { x = bw3; base = 192; r -= pc0 + pc1 + pc2; }
                for (int q = 0; q < r; ++q) x &= x - 1;  // drop r lowest set bits
                val = pzs[(l << 8) + base + (__ffsll(x) - 1)];
            }
            vv[sel] = __shfl(val, src, 64);
        }
        if (lane == 0) {
            float med = 0.5f * (vv[0] + vv[1]);
            out[og] = (med + 48.0f) * (1.0f / 96.0f);
        }
    }
}

extern "C" void kernel_launch(void* const* d_in, const int* in_sizes, int n_in,
                              void* d_out, int out_size, void* d_ws, size_t ws_size,
                              hipStream_t stream) {
    const float* pts = (const float*)d_in[0];
    float* out = (float*)d_out;

    char* ws = (char*)d_ws;
    float* nn2p      = (float*)(ws + 0);
    int* rkp         = (int*)(ws + 2097152);
    float2* pxy      = (float2*)(ws + 4194304);
    float* pzs       = (float*)(ws + 4259840);
    double* sum_part = (double*)(ws + 4292608);

    k_nn_rank<<<dim3(32, NSL), 256, 0, stream>>>(pts, nn2p, rkp);
    k_mid<<<32, 256, 0, stream>>>(pts, nn2p, rkp, pxy, pzs, sum_part);
    k_median<<<dim3(6, 96), 256, 0, stream>>>(pxy, pzs, sum_part, out);
}

// Round 9
// 106.544 us; speedup vs baseline: 2.7118x; 1.0737x over previous
//
#include <hip/hip_runtime.h>
#include <hip/hip_bf16.h>

#define NPTS 8192
#define NSL 64          // j-slices (128 points each)
#define HF 96.0f

// Workspace layout (bytes):
//   0        : float  nn2p[64][8192]   partial min d2 (unclamped) per (slice, i)
//   2097152  : int    rkp [64][8192]   partial pz-rank per (slice, i)
//   4194304  : float2 pxy[8192]        (px,py) sorted by pz
//   4259840  : float  pzs[8192]
//   4292608  : double sum_part[32]     per-block partial sums of nn_dist
// No init kernel / atomics: every cell written exactly once.
// Session lessons: coop grid.sync ~100us/sync (R7) -> keep 3 launches.
// 16-col k_median regressed (R8) -> keep 8-col. R4 config = best (107.5us).

// monotone (z, idx) -> u64 key; strict total order, one u64 compare per pair
__device__ __forceinline__ unsigned long long zkey(float z, int idx) {
    unsigned u = __float_as_uint(z);
    unsigned m = (unsigned)((int)u >> 31) | 0x80000000u;  // neg: FFFFFFFF, pos: 80000000
    return ((unsigned long long)(u ^ m) << 13) | (unsigned)idx;
}

// grid (32 i-blocks, 64 j-slices of 128), block 256 -> 2048 blocks, 8/CU.
__global__ __launch_bounds__(256) void k_nn_rank(const float* __restrict__ pts,
                                                 float* __restrict__ nn2p,
                                                 int* __restrict__ rkp) {
    __shared__ float4 s4[128];               // (px, py, pz, sq)
    __shared__ unsigned long long sk[128];   // z-order key
    const int tid = threadIdx.x;
    const int bx = blockIdx.x, by = blockIdx.y;
    const int i = bx * 256 + tid;
    const int j0 = by * 128;
    if (tid < 128) {
        int j = j0 + tid;
        float x = pts[3 * j + 0] * HF;
        float y = pts[3 * j + 1] * HF;
        float z = pts[3 * j + 2] * HF;
        s4[tid] = make_float4(x, y, z, x * x + y * y + z * z);
        sk[tid] = zkey(z, j);
    }
    const float xi = pts[3 * i + 0] * HF;
    const float yi = pts[3 * i + 1] * HF;
    const float zi = pts[3 * i + 2] * HF;
    const float sqi = xi * xi + yi * yi + zi * zi;
    const unsigned long long ki = zkey(zi, i);
    __syncthreads();

    float mn = 3.0e38f;
    int rk = 0;
    // self-pair occurs iff this j-slice covers i; condition is wave-uniform
    // (tid>>7 constant within a wave), so no divergence.
    const bool has_self = (by == 2 * bx + (tid >> 7));
    if (!has_self) {
        #pragma unroll 8
        for (int k = 0; k < 128; ++k) {
            float4 p = s4[k];
            // reference formula: sq_i + sq_j - 2*dot
            float d2 = sqi + p.w - 2.0f * (xi * p.x + yi * p.y + zi * p.z);
            mn = fminf(mn, d2);
            rk += (int)(sk[k] < ki);   // stable pz rank (index tiebreak)
        }
    } else {
        const int self_k = tid & 127;
        #pragma unroll 8
        for (int k = 0; k < 128; ++k) {
            float4 p = s4[k];
            float d2 = sqi + p.w - 2.0f * (xi * p.x + yi * p.y + zi * p.z);
            if (k != self_k) mn = fminf(mn, d2);
            rk += (int)(sk[k] < ki);
        }
    }
    nn2p[by * NPTS + i] = mn;   // coalesced, written exactly once
    rkp [by * NPTS + i] = rk;
}

// grid 32, block 256. Reduce partials -> nn_dist + total rank; scatter into
// pz-sorted order; per-block double partial sum of nn_dist.
__global__ __launch_bounds__(256) void k_mid(const float* __restrict__ pts,
                                             const float* __restrict__ nn2p,
                                             const int* __restrict__ rkp,
                                             float2* __restrict__ pxy,
                                             float* __restrict__ pzs,
                                             double* __restrict__ sum_part) {
    const int t = threadIdx.x;
    const int i = blockIdx.x * 256 + t;
    float mn = 3.0e38f;
    int rk = 0;
    #pragma unroll 8
    for (int s = 0; s < NSL; ++s) {
        mn = fminf(mn, nn2p[s * NPTS + i]);   // coalesced across threads
        rk += rkp[s * NPTS + i];
    }
    // clamp commutes with min across slices: min_s max(m_s,0) == max(min_s,0)
    const float nnd = sqrtf(fmaxf(mn, 0.0f));
    pxy[rk] = make_float2(pts[3 * i + 0] * HF, pts[3 * i + 1] * HF);
    pzs[rk] = pts[3 * i + 2] * HF;

    double acc = (double)nnd;
    #pragma unroll
    for (int off = 32; off > 0; off >>= 1) acc += __shfl_down(acc, off, 64);
    __shared__ double sw[4];
    if ((t & 63) == 0) sw[t >> 6] = acc;
    __syncthreads();
    if (t == 0) sum_part[blockIdx.x] = sw[0] + sw[1] + sw[2] + sw[3];
}

// One block per (row, group of 8 cols): 12x96 blocks. Thread t owns point
// 256k+t of chunk k (pz-sorted) -> coalesced float2 loads. Membership as
// per-wave 64-bit ballots in LDS; rank selection per-wave in the epilogue.
// delta2 finalized per-block from the 32 double partials (deterministic ->
// identical in every block).
// NOTE: replicates reference exactly: px upper bound uses Yr (row-uniform), not Xr.
__global__ __launch_bounds__(256) void k_median(const float2* __restrict__ pxy,
                                                const float* __restrict__ pzs,
                                                const double* __restrict__ sum_part,
                                                float* __restrict__ out) {
    __shared__ unsigned long long bal[8][4][32];  // [cell][wave][chunk]
    __shared__ float s_dd;
    const int t = threadIdx.x;
    const int lane = t & 63;
    const int w = t >> 6;
    const int row = blockIdx.y;      // 96
    const int cg = blockIdx.x;       // 12 col-groups of 8
    if (t == 0) {
        double s = 0.0;
        #pragma unroll
        for (int b = 0; b < 32; ++b) s += sum_part[b];
        float mean = (float)(s / (double)NPTS);
        float avg = 3.0f * mean;     // M_FACTOR * mean
        s_dd = 3.0f * avg;           // M_FACTOR * avg
    }
    __syncthreads();
    const float d = s_dd;
    const float Yf = (float)(row - 48);
    const float ylo = Yf - d, yhi = Yf + d, xhi = Yf + d;
    float xlo[8];
    #pragma unroll
    for (int c = 0; c < 8; ++c) xlo[c] = (float)(cg * 8 + c - 48) - d;

    #pragma unroll 4
    for (int k = 0; k < 32; ++k) {
        float2 p = pxy[(k << 8) + t];
        bool pre = (p.y >= ylo) && (p.y <= yhi) && (p.x <= xhi);
        unsigned long long b[8];
        #pragma unroll
        for (int c = 0; c < 8; ++c) b[c] = __ballot(pre && (p.x >= xlo[c]));
        if (lane == 0) {
            #pragma unroll
            for (int c = 0; c < 8; ++c) bal[c][w][k] = b[c];
        }
    }
    __syncthreads();

    // wave w handles cells 2w and 2w+1; lanes 0..31 each own one chunk
    #pragma unroll
    for (int c2 = 0; c2 < 2; ++c2) {
        const int c = w * 2 + c2;
        const int l = (lane < 32) ? lane : 31;
        const unsigned long long bw0 = bal[c][0][l];
        const unsigned long long bw1 = bal[c][1][l];
        const unsigned long long bw2 = bal[c][2][l];
        const unsigned long long bw3 = bal[c][3][l];
        const int cnt = __popcll(bw0) + __popcll(bw1) + __popcll(bw2) + __popcll(bw3);
        const int cl = (lane < 32) ? cnt : 0;
        int incl = cl;
        #pragma unroll
        for (int off = 1; off < 64; off <<= 1) {
            int v = __shfl_up(incl, off, 64);
            if (lane >= off) incl += v;
        }
        const int ct = __shfl(incl, 63, 64);  // total count c
        const int og = row * 96 + cg * 8 + c;
        if (ct == 0) {
            if (lane == 0) out[og] = 0.0f;
            continue;
        }
        const int excl = incl - cl;
        float vv[2];
        #pragma unroll
        for (int sel = 0; sel < 2; ++sel) {
            const int target = sel ? (ct >> 1) : ((ct - 1) >> 1);
            const bool pred = (lane < 32) && (target >= excl) && (target < excl + cl);
            unsigned long long bm = __ballot(pred);
            int src = __ffsll(bm) - 1;  // exactly one lane holds the target
            float val = 0.0f;
            if (pred) {
                int r = target - excl;
                int pc0 = __popcll(bw0), pc1 = __popcll(bw1), pc2 = __popcll(bw2);
                unsigned long long x;
                int base;
                if (r < pc0)              { x = bw0; base = 0; }
                else if (r < pc0 + pc1)   { x = bw1; base = 64;  r -= pc0; }
                else if (r < pc0+pc1+pc2) { x = bw2; base = 128; r -= pc0 + pc1; }
                else                      { x = bw3; base = 192; r -= pc0 + pc1 + pc2; }
                for (int q = 0; q < r; ++q) x &= x - 1;  // drop r lowest set bits
                val = pzs[(l << 8) + base + (__ffsll(x) - 1)];
            }
            vv[sel] = __shfl(val, src, 64);
        }
        if (lane == 0) {
            float med = 0.5f * (vv[0] + vv[1]);
            out[og] = (med + 48.0f) * (1.0f / 96.0f);
        }
    }
}

extern "C" void kernel_launch(void* const* d_in, const int* in_sizes, int n_in,
                              void* d_out, int out_size, void* d_ws, size_t ws_size,
                              hipStream_t stream) {
    const float* pts = (const float*)d_in[0];
    float* out = (float*)d_out;

    char* ws = (char*)d_ws;
    float* nn2p      = (float*)(ws + 0);
    int* rkp         = (int*)(ws + 2097152);
    float2* pxy      = (float2*)(ws + 4194304);
    float* pzs       = (float*)(ws + 4259840);
    double* sum_part = (double*)(ws + 4292608);

    k_nn_rank<<<dim3(32, NSL), 256, 0, stream>>>(pts, nn2p, rkp);
    k_mid<<<32, 256, 0, stream>>>(pts, nn2p, rkp, pxy, pzs, sum_part);
    k_median<<<dim3(12, 96), 256, 0, stream>>>(pxy, pzs, sum_part, out);
}